// Round 11
// baseline (249.705 us; speedup 1.0000x reference)
//
#include <hip/hip_runtime.h>
#include <cstdint>

#define C_ 128
#define L_ 16
#define G_ 4
#define H_ 56
#define W_ 56
#define HW_ 3136
#define CH_ 4                      // channels per chunk
#define NCK_ 8                     // chunks
#define RS_ 68                     // xs row stride: 17 x 16B blocks (bank-rotating)
#define NROW_ 10                   // halo rows per channel (h0-3 .. h0+6)
#define XS_F (CH_ * NROW_ * RS_)   // 2720 floats per chunk buffer
#define XTASK_ (CH_ * NROW_ * 17)  // 680 16B staging tasks per chunk
#define WL_F 2048                  // weights [c(32)][dy(8)][dx(8)]
#define LDS_F (WL_F + 2 * XS_F)    // 7488 floats
#define PAD_F 768                  // -> 33024 B total: exactly 4 blocks/CU

typedef float f4 __attribute__((ext_vector_type(4)));
typedef __attribute__((address_space(3))) uint32_t lds_u32;
typedef const __attribute__((address_space(1))) uint32_t glb_u32;

// Block = (b, t, g, htile of 4 rows), 256 thr = 8 tx x 4 h x 8 dy-slots
// (dy==7 idle). r9 structure, with three LDS-pipe cuts:
//  - weights in LDS transposed [c][dy][8] -> 2 x ds_read_b128 per ci
//  - x1 from GLOBAL (same line across the 7 dy-slots -> L1 broadcast)
//  - xs row stride 17 blocks: bank group = (row+block) mod 8 rotates, so the
//    wave's read spreads ~7 distinct addrs/bank group (optimal); pad block 16
//    and value blocks 0/15 stay zero from init (never staged, never read-hot).
// LDS padded to 33 KB: exactly 4 blocks/CU so the allocator targets
// 4 waves/SIMD (128-VGPR budget; r9-validated against squeeze-spill).
__global__ __launch_bounds__(256, 2)
void wcorr(const float* __restrict__ x, const float* __restrict__ wgt,
           float* __restrict__ out) {
  __shared__ float lds[LDS_F];
  __shared__ float lds_pad[PAD_F];
  asm volatile("" :: "v"(&lds_pad[threadIdx.x & 63]));  // keep pad allocated

  int bid = blockIdx.x;
  // bijective XCD swizzle: nwg = 7168 = 8*896; htile fastest (halo-row reuse),
  // then t, then g,b: one (b,g) stays on one XCD's L2.
  int wid = (bid & 7) * 896 + (bid >> 3);
  int htile = wid % 14;
  int rest = wid / 14;             // (b*4+g)*16 + t
  int t = rest & 15;
  int bg = rest >> 4;
  int g = bg & 3;
  int b = bg >> 2;
  int h0 = htile * 4;

  int tid = threadIdx.x;
  int tx = tid & 7;
  int slot = tid >> 3;
  int h = slot & 3;
  int dy = slot >> 2;              // 0..7 (7 = idle)
  bool active = (dy < 7) && (tx < 7);
  int dyc = dy < 7 ? dy : 6;       // clamp idle lanes to safe addresses
  int txc = tx < 7 ? tx : 6;
  int r = h + dyc;                 // xs local row 0..9 (global hh = h0-3+r)
  int t1 = t > 0 ? t - 1 : 0;
  int w0 = 8 * txc;

  for (int i = tid; i < LDS_F; i += 256) lds[i] = 0.0f;
  __syncthreads();                 // zero visible before ds_writes/stages

  const size_t cstride = (size_t)L_ * HW_;
  const float* xg = x + ((size_t)b * C_ + (size_t)g * 32) * cstride;
  const float* x1b = xg + (size_t)t1 * HW_ + (size_t)(h0 + h) * W_ + w0;

  // ---- stage weights once, transposed [c][dy][8], 1/32 folded ----
  {
    const float sc = 1.0f / 32.0f;
    const float* wsrc = wgt + (size_t)(g * 32) * (L_ * 49) + t * 49;
    #pragma unroll
    for (int j = 0; j < 8; ++j) {
      int idx = tid + j * 256;     // 0..2047
      int c = idx >> 6;
      int rem = idx & 63;
      int dyy = rem >> 3, dxx = rem & 7;
      float v = 0.0f;
      if (dyy < 7 && dxx < 7)
        v = wsrc[(size_t)c * (L_ * 49) + dyy * 7 + dxx] * sc;
      lds[idx] = v;
    }
  }

  // ---- xs staging: task tau in [0,680) -> 16B slot at lds[fb + tau*4].
  // row = tau/17 (magic), vb = tau%17; vb==16 is the bank-rotation pad,
  // vb 0/15 are window zero-pads -> all skipped (stay zero).
  auto stage = [&](int tau, int k, bool on) {
    int fb = WL_F + (k & 1) * XS_F;
    int c0 = k * CH_;
    int row = (tau * 965) >> 14;   // tau/17 for tau < 680
    int vb = tau - row * 17;
    int ci = (row * 205) >> 11;    // row/10 for row < 40
    int rr = row - ci * 10;
    int hh = h0 - 3 + rr;
    bool ok = on && (vb >= 1) && (vb <= 14) && (hh >= 0) && (hh < H_);
    const float* src = xg + (size_t)(c0 + ci) * cstride + (size_t)t * HW_
                          + hh * W_ + (vb * 4 - 4);
    float* dst = &lds[fb + (tau & ~63) * 4];   // wave-uniform base
    if (ok)
      __builtin_amdgcn_global_load_lds((glb_u32*)src, (lds_u32*)dst, 16, 0, 0);
  };
  auto stage_chunk = [&](int k) {
    stage(tid, k, true);
    stage(tid + 256, k, true);
    stage(tid + 512, k, tid + 512 < XTASK_);
  };

  float acc[7][8];
  #pragma unroll
  for (int i = 0; i < 7; ++i)
    #pragma unroll
    for (int p = 0; p < 8; ++p) acc[i][p] = 0.0f;

  stage_chunk(0);
  __syncthreads();                 // drains vmcnt(0): chunk 0 + weights ready

  #pragma unroll 2
  for (int k = 0; k < NCK_; ++k) {
    if (k + 1 < NCK_) stage_chunk(k + 1);   // issue-early: flies during compute
    int fb = WL_F + (k & 1) * XS_F;
    int c0 = k * CH_;
    #pragma unroll
    for (int ci = 0; ci < CH_; ++ci) {
      const f4* xsrow = (const f4*)&lds[fb + (ci * NROW_ + r) * RS_];
      f4 q0 = xsrow[2 * txc + 0];
      f4 q1 = xsrow[2 * txc + 1];
      f4 q2 = xsrow[2 * txc + 2];
      f4 q3 = xsrow[2 * txc + 3];
      const f4* wl = (const f4*)&lds[(c0 + ci) * 64 + dyc * 8];
      f4 wv0 = wl[0];
      f4 wv1 = wl[1];
      const float* x1p = x1b + (size_t)(c0 + ci) * cstride;   // global, L1-hot
      f4 a0 = *(const f4*)(x1p);
      f4 a1 = *(const f4*)(x1p + 4);
      float w7[7] = {wv0.x, wv0.y, wv0.z, wv0.w, wv1.x, wv1.y, wv1.z};
      // rr_[i] = value at col w0-4+i; (p,dx) needs col w0+p+dx-3 -> rr_[p+dx+1]
      float rr_[16] = {q0.x, q0.y, q0.z, q0.w, q1.x, q1.y, q1.z, q1.w,
                       q2.x, q2.y, q2.z, q2.w, q3.x, q3.y, q3.z, q3.w};
      float x1v[8] = {a0.x, a0.y, a0.z, a0.w, a1.x, a1.y, a1.z, a1.w};
      #pragma unroll
      for (int dxx = 0; dxx < 7; ++dxx) {
        #pragma unroll
        for (int p = 0; p < 8; ++p) {
          acc[dxx][p] = fmaf(w7[dxx], x1v[p] * rr_[p + dxx + 1], acc[dxx][p]);
        }
      }
    }
    __syncthreads();   // compute(k) done; stage(k+1) drained at barrier
  }

  if (active) {
    #pragma unroll
    for (int dxx = 0; dxx < 7; ++dxx) {
      int och = (dy * 7 + dxx) * G_ + g;
      float* op = out + (((size_t)b * 196 + och) * L_ + t) * (size_t)HW_
                      + (size_t)(h0 + h) * W_ + w0;
      f4 o0 = {acc[dxx][0], acc[dxx][1], acc[dxx][2], acc[dxx][3]};
      f4 o1 = {acc[dxx][4], acc[dxx][5], acc[dxx][6], acc[dxx][7]};
      __builtin_nontemporal_store(o0, (f4*)op);
      __builtin_nontemporal_store(o1, (f4*)(op + 4));
    }
  }
}

extern "C" void kernel_launch(void* const* d_in, const int* in_sizes, int n_in,
                              void* d_out, int out_size, void* d_ws, size_t ws_size,
                              hipStream_t stream) {
  const float* x = (const float*)d_in[0];
  const float* w = (const float*)d_in[1];
  float* o = (float*)d_out;
  dim3 grid(7168), block(256);
  hipLaunchKernelGGL(wcorr, grid, block, 0, stream, x, w, o);
}

// Round 12
// 237.935 us; speedup vs baseline: 1.0495x; 1.0495x over previous
//
#include <hip/hip_runtime.h>
#include <cstdint>

#define C_ 128
#define L_ 16
#define G_ 4
#define H_ 56
#define W_ 56
#define HW_ 3136
#define CH_ 4                      // channels per chunk
#define NCK_ 8                     // chunks
#define RS_ 64                     // xs row stride: 16 x 16B blocks, XOR swizzle
#define NROW_ 10                   // halo rows per channel (h0-3 .. h0+6)
#define XS_F (CH_ * NROW_ * RS_)   // 2560 floats per chunk buffer
#define XTASK_ (CH_ * NROW_ * 16)  // 640 16B staging tasks per chunk
#define WL_F 2048                  // weights [c(32)][dy(8)][dx(8)]
#define LDS_F (WL_F + 2 * XS_F)    // 7168 floats
#define PAD_F 1088                 // -> 33024 B total: exactly 4 blocks/CU

typedef float f4 __attribute__((ext_vector_type(4)));
typedef __attribute__((address_space(3))) uint32_t lds_u32;
typedef const __attribute__((address_space(1))) uint32_t glb_u32;

// Block = (b, t, g, htile of 4 rows), 256 thr = 8 tx x 4 h x 8 dy-slots
// (dy==7 idle). r9 xs scheme (RS 64 + XOR(r&7), 7.3M-conflict-proven) +
// r11 transposed weights [c][dy][8] (2 x b128, broadcast, conflict-free) +
// x1 from GLOBAL with loads hoisted ABOVE stage_chunk(k+1): vmcnt queue
// becomes [x1 x8, stage x3], so consuming x1 in compute(k) leaves the
// next-chunk prefetch outstanding (r11 had the reverse order, which
// serialized the prefetch into the compute phase).
// LDS padded to 33 KB: exactly 4 blocks/CU -> allocator targets 4 waves/SIMD
// (128-VGPR budget; r9-validated against the squeeze-to-64 spill).
__global__ __launch_bounds__(256, 2)
void wcorr(const float* __restrict__ x, const float* __restrict__ wgt,
           float* __restrict__ out) {
  __shared__ float lds[LDS_F];
  __shared__ float lds_pad[PAD_F];
  asm volatile("" :: "v"(&lds_pad[threadIdx.x & 63]));  // keep pad allocated

  int bid = blockIdx.x;
  // bijective XCD swizzle: nwg = 7168 = 8*896; htile fastest (halo-row reuse),
  // then t, then g,b: one (b,g) stays on one XCD's L2.
  int wid = (bid & 7) * 896 + (bid >> 3);
  int htile = wid % 14;
  int rest = wid / 14;             // (b*4+g)*16 + t
  int t = rest & 15;
  int bg = rest >> 4;
  int g = bg & 3;
  int b = bg >> 2;
  int h0 = htile * 4;

  int tid = threadIdx.x;
  int tx = tid & 7;
  int slot = tid >> 3;
  int h = slot & 3;
  int dy = slot >> 2;              // 0..7 (7 = idle)
  bool active = (dy < 7) && (tx < 7);
  int dyc = dy < 7 ? dy : 6;       // clamp idle lanes to safe addresses
  int txc = tx < 7 ? tx : 6;
  int r = h + dyc;                 // xs local row 0..9 (global hh = h0-3+r)
  int t1 = t > 0 ? t - 1 : 0;
  int w0 = 8 * txc;

  for (int i = tid; i < LDS_F; i += 256) lds[i] = 0.0f;
  __syncthreads();                 // zero visible before ds_writes/stages

  const size_t cstride = (size_t)L_ * HW_;
  const float* xg = x + ((size_t)b * C_ + (size_t)g * 32) * cstride;
  const float* x1b = xg + (size_t)t1 * HW_ + (size_t)(h0 + h) * W_ + w0;

  // ---- stage weights once, transposed [c][dy][8], 1/32 folded ----
  {
    const float sc = 1.0f / 32.0f;
    const float* wsrc = wgt + (size_t)(g * 32) * (L_ * 49) + t * 49;
    #pragma unroll
    for (int j = 0; j < 8; ++j) {
      int idx = tid + j * 256;     // 0..2047
      int c = idx >> 6;
      int rem = idx & 63;
      int dyy = rem >> 3, dxx = rem & 7;
      float v = 0.0f;
      if (dyy < 7 && dxx < 7)
        v = wsrc[(size_t)c * (L_ * 49) + dyy * 7 + dxx] * sc;
      lds[idx] = v;
    }
  }

  // ---- xs staging: task tau in [0,640): row = tau>>4 (ci = row/10,
  // rr = row%10), sb = tau&15 = storage block; slot sb receives value block
  // vb = sb ^ (rr&7) (pre-swizzled global source, linear LDS dest).
  // vb 0/15 and OOB rows skipped -> stay zero (window zero-pad).
  auto stage = [&](int tau, int k, bool on) {
    int fb = WL_F + (k & 1) * XS_F;
    int c0 = k * CH_;
    int row = tau >> 4;
    int sb = tau & 15;
    int ci = (row * 205) >> 11;    // row/10 for row < 40
    int rr = row - ci * 10;
    int vb = sb ^ (rr & 7);
    int hh = h0 - 3 + rr;
    bool ok = on && (vb >= 1) && (vb <= 14) && (hh >= 0) && (hh < H_);
    const float* src = xg + (size_t)(c0 + ci) * cstride + (size_t)t * HW_
                          + hh * W_ + (vb * 4 - 4);
    float* dst = &lds[fb + (tau & ~63) * 4];   // wave-uniform base
    if (ok)
      __builtin_amdgcn_global_load_lds((glb_u32*)src, (lds_u32*)dst, 16, 0, 0);
  };
  auto stage_chunk = [&](int k) {
    stage(tid, k, true);
    stage(tid + 256, k, true);
    stage(tid + 512, k, tid + 512 < XTASK_);   // waves 0,1 only (wave-uniform)
  };

  float acc[7][8];
  #pragma unroll
  for (int i = 0; i < 7; ++i)
    #pragma unroll
    for (int p = 0; p < 8; ++p) acc[i][p] = 0.0f;

  stage_chunk(0);
  __syncthreads();                 // drains vmcnt(0): chunk 0 + weights ready

  #pragma unroll 1
  for (int k = 0; k < NCK_; ++k) {
    int fb = WL_F + (k & 1) * XS_F;
    int c0 = k * CH_;

    // x1 loads FIRST (before next-chunk stage issue): consuming these only
    // waits vmcnt down to the stage count; the prefetch stays outstanding.
    f4 xa[CH_][2];
    #pragma unroll
    for (int ci = 0; ci < CH_; ++ci) {
      const float* x1p = x1b + (size_t)(c0 + ci) * cstride;  // L1-broadcast
      xa[ci][0] = *(const f4*)(x1p);
      xa[ci][1] = *(const f4*)(x1p + 4);
    }
    __builtin_amdgcn_sched_barrier(0);
    if (k + 1 < NCK_) stage_chunk(k + 1);      // issue-early prefetch
    __builtin_amdgcn_sched_barrier(0);

    int s = r & 7;
    #pragma unroll
    for (int ci = 0; ci < CH_; ++ci) {
      const f4* xsrow = (const f4*)&lds[fb + (ci * NROW_ + r) * RS_];
      f4 q0 = xsrow[(2 * txc + 0) ^ s];
      f4 q1 = xsrow[(2 * txc + 1) ^ s];
      f4 q2 = xsrow[(2 * txc + 2) ^ s];
      f4 q3 = xsrow[(2 * txc + 3) ^ s];
      const f4* wl = (const f4*)&lds[(c0 + ci) * 64 + dyc * 8];
      f4 wv0 = wl[0];
      f4 wv1 = wl[1];
      float w7[7] = {wv0.x, wv0.y, wv0.z, wv0.w, wv1.x, wv1.y, wv1.z};
      // rr_[i] = value at col w0-4+i; (p,dx) needs col w0+p+dx-3 -> rr_[p+dx+1]
      float rr_[16] = {q0.x, q0.y, q0.z, q0.w, q1.x, q1.y, q1.z, q1.w,
                       q2.x, q2.y, q2.z, q2.w, q3.x, q3.y, q3.z, q3.w};
      float x1v[8] = {xa[ci][0].x, xa[ci][0].y, xa[ci][0].z, xa[ci][0].w,
                      xa[ci][1].x, xa[ci][1].y, xa[ci][1].z, xa[ci][1].w};
      #pragma unroll
      for (int dxx = 0; dxx < 7; ++dxx) {
        #pragma unroll
        for (int p = 0; p < 8; ++p) {
          acc[dxx][p] = fmaf(w7[dxx], x1v[p] * rr_[p + dxx + 1], acc[dxx][p]);
        }
      }
    }
    __syncthreads();   // compute(k) done; stage(k+1) drained at barrier
  }

  if (active) {
    #pragma unroll
    for (int dxx = 0; dxx < 7; ++dxx) {
      int och = (dy * 7 + dxx) * G_ + g;
      float* op = out + (((size_t)b * 196 + och) * L_ + t) * (size_t)HW_
                      + (size_t)(h0 + h) * W_ + w0;
      f4 o0 = {acc[dxx][0], acc[dxx][1], acc[dxx][2], acc[dxx][3]};
      f4 o1 = {acc[dxx][4], acc[dxx][5], acc[dxx][6], acc[dxx][7]};
      __builtin_nontemporal_store(o0, (f4*)op);
      __builtin_nontemporal_store(o1, (f4*)(op + 4));
    }
  }
}

extern "C" void kernel_launch(void* const* d_in, const int* in_sizes, int n_in,
                              void* d_out, int out_size, void* d_ws, size_t ws_size,
                              hipStream_t stream) {
  const float* x = (const float*)d_in[0];
  const float* w = (const float*)d_in[1];
  float* o = (float*)d_out;
  dim3 grid(7168), block(256);
  hipLaunchKernelGGL(wcorr, grid, block, 0, stream, x, w, o);
}

// Round 13
// 235.031 us; speedup vs baseline: 1.0624x; 1.0124x over previous
//
#include <hip/hip_runtime.h>
#include <cstdint>

#define C_ 128
#define L_ 16
#define G_ 4
#define H_ 56
#define W_ 56
#define HW_ 3136
#define CH_ 4                      // channels per chunk
#define NCK_ 8                     // chunks
#define RS_ 64                     // xs row stride: 16 x 16B blocks, XOR swizzle
#define NROW_ 10                   // halo rows per channel (h0-3 .. h0+6)
#define XS_F (CH_ * NROW_ * RS_)   // 2560 floats per chunk buffer
#define XTASK_ (CH_ * NROW_ * 16)  // 640 16B staging tasks per chunk
#define WL_F 2048                  // weights [c(32)][dy(8)][dx(8)]
#define NBUF_ 3
#define LDS_F (WL_F + NBUF_ * XS_F)  // 9728 floats = 38912 B -> 4 blocks/CU

typedef float f4 __attribute__((ext_vector_type(4)));
typedef __attribute__((address_space(3))) uint32_t lds_u32;
typedef const __attribute__((address_space(1))) uint32_t glb_u32;

// Block = (b, t, g, htile of 4 rows), 256 thr = 8 tx x 4 h x 8 dy-slots
// (dy==7 idle). TRIPLE-buffered xs staging with barrier-then-stage ordering:
//   loop k: { __syncthreads(); stage(k+2); compute(k); }
// At barrier k the only outstanding prefetch is stage(k+1), issued one full
// round (~10K cyc) earlier -> the implicit vmcnt(0) drain is free. stage(k+2)
// is issued AFTER the barrier so it is never drained fresh (r9-r12 lost ~50%
// of every round to this drain tail). Race-free: barrier k follows
// compute(k-1), the last reader of buffer (k+2)%3, in program order.
// xs: RS 64 + XOR(r&7) swizzle (both-sides, pre-swizzled global source,
// linear LDS dest). Weights transposed [c][dy][8] -> 2 x b128 broadcast.
// x1 from global inside compute (L1-broadcast across the 7 dy-slots).
__global__ __launch_bounds__(256, 2)
void wcorr(const float* __restrict__ x, const float* __restrict__ wgt,
           float* __restrict__ out) {
  __shared__ float lds[LDS_F];

  int bid = blockIdx.x;
  // bijective XCD swizzle: nwg = 7168 = 8*896; htile fastest (halo-row reuse),
  // then t, then g,b: one (b,g) stays on one XCD's L2.
  int wid = (bid & 7) * 896 + (bid >> 3);
  int htile = wid % 14;
  int rest = wid / 14;             // (b*4+g)*16 + t
  int t = rest & 15;
  int bg = rest >> 4;
  int g = bg & 3;
  int b = bg >> 2;
  int h0 = htile * 4;

  int tid = threadIdx.x;
  int tx = tid & 7;
  int slot = tid >> 3;
  int h = slot & 3;
  int dy = slot >> 2;              // 0..7 (7 = idle)
  bool active = (dy < 7) && (tx < 7);
  int dyc = dy < 7 ? dy : 6;       // clamp idle lanes to safe addresses
  int txc = tx < 7 ? tx : 6;
  int r = h + dyc;                 // xs local row 0..9 (global hh = h0-3+r)
  int t1 = t > 0 ? t - 1 : 0;
  int w0 = 8 * txc;

  // zero only the xs region (pad slots persist as zero across buffer reuse;
  // weights region is fully overwritten below)
  for (int i = WL_F + tid; i < LDS_F; i += 256) lds[i] = 0.0f;
  __syncthreads();                 // zeros visible before staging overwrites

  const size_t cstride = (size_t)L_ * HW_;
  const float* xg = x + ((size_t)b * C_ + (size_t)g * 32) * cstride;
  const float* x1b = xg + (size_t)t1 * HW_ + (size_t)(h0 + h) * W_ + w0;

  // ---- stage weights once, transposed [c][dy][8], 1/32 folded ----
  {
    const float sc = 1.0f / 32.0f;
    const float* wsrc = wgt + (size_t)(g * 32) * (L_ * 49) + t * 49;
    #pragma unroll
    for (int j = 0; j < 8; ++j) {
      int idx = tid + j * 256;     // 0..2047
      int c = idx >> 6;
      int rem = idx & 63;
      int dyy = rem >> 3, dxx = rem & 7;
      float v = 0.0f;
      if (dyy < 7 && dxx < 7)
        v = wsrc[(size_t)c * (L_ * 49) + dyy * 7 + dxx] * sc;
      lds[idx] = v;
    }
  }

  // ---- xs staging: task tau in [0,640): row = tau>>4 (ci = row/10,
  // rr = row%10), sb = tau&15 = storage block receiving value block
  // vb = sb ^ (rr&7) (pre-swizzled global source, linear LDS dest).
  // vb 0/15 and OOB rows skipped -> stay zero (window zero-pad).
  auto stage = [&](int tau, int fb, int c0, bool on) {
    int row = tau >> 4;
    int sb = tau & 15;
    int ci = (row * 205) >> 11;    // row/10 for row < 40
    int rr = row - ci * 10;
    int vb = sb ^ (rr & 7);
    int hh = h0 - 3 + rr;
    bool ok = on && (vb >= 1) && (vb <= 14) && (hh >= 0) && (hh < H_);
    const float* src = xg + (size_t)(c0 + ci) * cstride + (size_t)t * HW_
                          + hh * W_ + (vb * 4 - 4);
    float* dst = &lds[fb + (tau & ~63) * 4];   // wave-uniform base
    if (ok)
      __builtin_amdgcn_global_load_lds((glb_u32*)src, (lds_u32*)dst, 16, 0, 0);
  };
  auto stage_chunk = [&](int fb, int c0) {
    stage(tid, fb, c0, true);
    stage(tid + 256, fb, c0, true);
    stage(tid + 512, fb, c0, tid + 512 < XTASK_);  // waves 0,1 (wave-uniform)
  };

  float acc[7][8];
  #pragma unroll
  for (int i = 0; i < 7; ++i)
    #pragma unroll
    for (int p = 0; p < 8; ++p) acc[i][p] = 0.0f;

  stage_chunk(WL_F, 0);                 // chunk 0 -> buf 0
  stage_chunk(WL_F + XS_F, CH_);        // chunk 1 -> buf 1

  int buf = 0, buf2 = 2;                // buf = k%3, buf2 = (k+2)%3
  #pragma unroll 1
  for (int k = 0; k < NCK_; ++k) {
    __syncthreads();   // drains stage(k+1) (issued a full round ago: free);
                       // all waves past compute(k-1) -> buffer (k+2)%3 free
    if (k + 2 < NCK_)
      stage_chunk(WL_F + buf2 * XS_F, (k + 2) * CH_);

    int fb = WL_F + buf * XS_F;
    int c0 = k * CH_;
    int s = r & 7;
    #pragma unroll
    for (int ci = 0; ci < CH_; ++ci) {
      const f4* xsrow = (const f4*)&lds[fb + (ci * NROW_ + r) * RS_];
      f4 q0 = xsrow[(2 * txc + 0) ^ s];
      f4 q1 = xsrow[(2 * txc + 1) ^ s];
      f4 q2 = xsrow[(2 * txc + 2) ^ s];
      f4 q3 = xsrow[(2 * txc + 3) ^ s];
      const f4* wl = (const f4*)&lds[(c0 + ci) * 64 + dyc * 8];
      f4 wv0 = wl[0];
      f4 wv1 = wl[1];
      const float* x1p = x1b + (size_t)(c0 + ci) * cstride;  // L1-broadcast
      f4 a0 = *(const f4*)(x1p);
      f4 a1 = *(const f4*)(x1p + 4);
      float w7[7] = {wv0.x, wv0.y, wv0.z, wv0.w, wv1.x, wv1.y, wv1.z};
      // rr_[i] = value at col w0-4+i; (p,dx) needs col w0+p+dx-3 -> rr_[p+dx+1]
      float rr_[16] = {q0.x, q0.y, q0.z, q0.w, q1.x, q1.y, q1.z, q1.w,
                       q2.x, q2.y, q2.z, q2.w, q3.x, q3.y, q3.z, q3.w};
      float x1v[8] = {a0.x, a0.y, a0.z, a0.w, a1.x, a1.y, a1.z, a1.w};
      #pragma unroll
      for (int dxx = 0; dxx < 7; ++dxx) {
        #pragma unroll
        for (int p = 0; p < 8; ++p) {
          acc[dxx][p] = fmaf(w7[dxx], x1v[p] * rr_[p + dxx + 1], acc[dxx][p]);
        }
      }
    }
    buf = (buf == 2) ? 0 : buf + 1;
    buf2 = (buf2 == 2) ? 0 : buf2 + 1;
  }

  if (active) {
    #pragma unroll
    for (int dxx = 0; dxx < 7; ++dxx) {
      int och = (dy * 7 + dxx) * G_ + g;
      float* op = out + (((size_t)b * 196 + och) * L_ + t) * (size_t)HW_
                      + (size_t)(h0 + h) * W_ + w0;
      f4 o0 = {acc[dxx][0], acc[dxx][1], acc[dxx][2], acc[dxx][3]};
      f4 o1 = {acc[dxx][4], acc[dxx][5], acc[dxx][6], acc[dxx][7]};
      __builtin_nontemporal_store(o0, (f4*)op);
      __builtin_nontemporal_store(o1, (f4*)(op + 4));
    }
  }
}

extern "C" void kernel_launch(void* const* d_in, const int* in_sizes, int n_in,
                              void* d_out, int out_size, void* d_ws, size_t ws_size,
                              hipStream_t stream) {
  const float* x = (const float*)d_in[0];
  const float* w = (const float*)d_in[1];
  float* o = (float*)d_out;
  dim3 grid(7168), block(256);
  hipLaunchKernelGGL(wcorr, grid, block, 0, stream, x, w, o);
}

// Round 14
// 232.919 us; speedup vs baseline: 1.0721x; 1.0091x over previous
//
#include <hip/hip_runtime.h>
#include <cstdint>

#define C_ 128
#define L_ 16
#define G_ 4
#define H_ 56
#define W_ 56
#define HW_ 3136
#define CH_ 4                      // channels per chunk
#define NCK_ 8                     // chunks
#define RS_ 64                     // xs row stride: 16 x 16B blocks, XOR swizzle
#define NROW_ 10                   // halo rows per channel (h0-3 .. h0+6)
#define XS_F (CH_ * NROW_ * RS_)   // 2560 floats per chunk buffer
#define XTASK_ (CH_ * NROW_ * 16)  // 640 16B staging tasks per chunk
#define WL_F 2048                  // weights [c(32)][dy(8)][dx(8)]
#define NBUF_ 2
#define LDS_F (WL_F + NBUF_ * XS_F)  // 7168 floats = 28672 B  <= 32768!

typedef float f4 __attribute__((ext_vector_type(4)));
typedef __attribute__((address_space(3))) uint32_t lds_u32;
typedef const __attribute__((address_space(1))) uint32_t glb_u32;

// Block = (b, t, g, htile of 4 rows), 256 thr = 8 tx x 4 h x 8 dy-slots
// (dy==7 idle). Double-buffered xs staging, loop: {sync; stage(k+1);
// compute(k)} — r13 proved the barrier's vmcnt-drain tail is cheap (3 us).
//
// THE change this round: total LDS = 28,672 B <= 32 KiB. Occupancy evidence
// (r1 23.3% @64K/2blk, r9 22.2% @35.3K/"4blk", r13 22.8% @38.9K/"4blk") says
// LDS allocates in 32 KiB granules: 33-39 KB occupied a 64 KB slot -> only
// 2 blocks/CU resident -> ~2 waves/SIMD -> latency-bound at 45% on both
// pipes. At 28.7 KB real 4 blocks fit (VGPR-capped), doubling TLP.
// xs: RS 64 + XOR(r&7) swizzle (both-sides: pre-swizzled global source,
// linear LDS dest). Weights transposed [c][dy][8] -> 2 x b128 broadcast.
// x1 from global inside compute (L1-broadcast across the 7 dy-slots).
__global__ __launch_bounds__(256, 2)
void wcorr(const float* __restrict__ x, const float* __restrict__ wgt,
           float* __restrict__ out) {
  __shared__ float lds[LDS_F];

  int bid = blockIdx.x;
  // bijective XCD swizzle: nwg = 7168 = 8*896; htile fastest (halo-row reuse),
  // then t, then g,b: one (b,g) stays on one XCD's L2.
  int wid = (bid & 7) * 896 + (bid >> 3);
  int htile = wid % 14;
  int rest = wid / 14;             // (b*4+g)*16 + t
  int t = rest & 15;
  int bg = rest >> 4;
  int g = bg & 3;
  int b = bg >> 2;
  int h0 = htile * 4;

  int tid = threadIdx.x;
  int tx = tid & 7;
  int slot = tid >> 3;
  int h = slot & 3;
  int dy = slot >> 2;              // 0..7 (7 = idle)
  bool active = (dy < 7) && (tx < 7);
  int dyc = dy < 7 ? dy : 6;       // clamp idle lanes to safe addresses
  int txc = tx < 7 ? tx : 6;
  int r = h + dyc;                 // xs local row 0..9 (global hh = h0-3+r)
  int t1 = t > 0 ? t - 1 : 0;
  int w0 = 8 * txc;

  // zero the xs region once (pad slots persist as zero across buffer reuse)
  for (int i = WL_F + tid; i < LDS_F; i += 256) lds[i] = 0.0f;
  __syncthreads();                 // zeros visible before staging overwrites

  const size_t cstride = (size_t)L_ * HW_;
  const float* xg = x + ((size_t)b * C_ + (size_t)g * 32) * cstride;
  const float* x1b = xg + (size_t)t1 * HW_ + (size_t)(h0 + h) * W_ + w0;

  // ---- stage weights once, transposed [c][dy][8], 1/32 folded ----
  {
    const float sc = 1.0f / 32.0f;
    const float* wsrc = wgt + (size_t)(g * 32) * (L_ * 49) + t * 49;
    #pragma unroll
    for (int j = 0; j < 8; ++j) {
      int idx = tid + j * 256;     // 0..2047
      int c = idx >> 6;
      int rem = idx & 63;
      int dyy = rem >> 3, dxx = rem & 7;
      float v = 0.0f;
      if (dyy < 7 && dxx < 7)
        v = wsrc[(size_t)c * (L_ * 49) + dyy * 7 + dxx] * sc;
      lds[idx] = v;
    }
  }

  // ---- xs staging: task tau in [0,640): row = tau>>4 (ci = row/10,
  // rr = row%10), sb = tau&15 = storage block receiving value block
  // vb = sb ^ (rr&7) (pre-swizzled global source, linear LDS dest).
  // vb 0/15 and OOB rows skipped -> stay zero (window zero-pad).
  auto stage = [&](int tau, int fb, int c0, bool on) {
    int row = tau >> 4;
    int sb = tau & 15;
    int ci = (row * 205) >> 11;    // row/10 for row < 40
    int rr = row - ci * 10;
    int vb = sb ^ (rr & 7);
    int hh = h0 - 3 + rr;
    bool ok = on && (vb >= 1) && (vb <= 14) && (hh >= 0) && (hh < H_);
    const float* src = xg + (size_t)(c0 + ci) * cstride + (size_t)t * HW_
                          + hh * W_ + (vb * 4 - 4);
    float* dst = &lds[fb + (tau & ~63) * 4];   // wave-uniform base
    if (ok)
      __builtin_amdgcn_global_load_lds((glb_u32*)src, (lds_u32*)dst, 16, 0, 0);
  };
  auto stage_chunk = [&](int fb, int c0) {
    stage(tid, fb, c0, true);
    stage(tid + 256, fb, c0, true);
    stage(tid + 512, fb, c0, tid + 512 < XTASK_);  // waves 0,1 (wave-uniform)
  };

  float acc[7][8];
  #pragma unroll
  for (int i = 0; i < 7; ++i)
    #pragma unroll
    for (int p = 0; p < 8; ++p) acc[i][p] = 0.0f;

  stage_chunk(WL_F, 0);                 // chunk 0 -> buf 0

  #pragma unroll 1
  for (int k = 0; k < NCK_; ++k) {
    __syncthreads();   // stage(k) (issued ~1 round ago) drained; weights
                       // visible (k=0); compute(k-1) done -> buf (k+1)&1 free
    if (k + 1 < NCK_)
      stage_chunk(WL_F + ((k + 1) & 1) * XS_F, (k + 1) * CH_);

    int fb = WL_F + (k & 1) * XS_F;
    int c0 = k * CH_;
    int s = r & 7;
    #pragma unroll
    for (int ci = 0; ci < CH_; ++ci) {
      const f4* xsrow = (const f4*)&lds[fb + (ci * NROW_ + r) * RS_];
      f4 q0 = xsrow[(2 * txc + 0) ^ s];
      f4 q1 = xsrow[(2 * txc + 1) ^ s];
      f4 q2 = xsrow[(2 * txc + 2) ^ s];
      f4 q3 = xsrow[(2 * txc + 3) ^ s];
      const f4* wl = (const f4*)&lds[(c0 + ci) * 64 + dyc * 8];
      f4 wv0 = wl[0];
      f4 wv1 = wl[1];
      const float* x1p = x1b + (size_t)(c0 + ci) * cstride;  // L1-broadcast
      f4 a0 = *(const f4*)(x1p);
      f4 a1 = *(const f4*)(x1p + 4);
      float w7[7] = {wv0.x, wv0.y, wv0.z, wv0.w, wv1.x, wv1.y, wv1.z};
      // rr_[i] = value at col w0-4+i; (p,dx) needs col w0+p+dx-3 -> rr_[p+dx+1]
      float rr_[16] = {q0.x, q0.y, q0.z, q0.w, q1.x, q1.y, q1.z, q1.w,
                       q2.x, q2.y, q2.z, q2.w, q3.x, q3.y, q3.z, q3.w};
      float x1v[8] = {a0.x, a0.y, a0.z, a0.w, a1.x, a1.y, a1.z, a1.w};
      #pragma unroll
      for (int dxx = 0; dxx < 7; ++dxx) {
        #pragma unroll
        for (int p = 0; p < 8; ++p) {
          acc[dxx][p] = fmaf(w7[dxx], x1v[p] * rr_[p + dxx + 1], acc[dxx][p]);
        }
      }
    }
  }

  if (active) {
    #pragma unroll
    for (int dxx = 0; dxx < 7; ++dxx) {
      int och = (dy * 7 + dxx) * G_ + g;
      float* op = out + (((size_t)b * 196 + och) * L_ + t) * (size_t)HW_
                      + (size_t)(h0 + h) * W_ + w0;
      f4 o0 = {acc[dxx][0], acc[dxx][1], acc[dxx][2], acc[dxx][3]};
      f4 o1 = {acc[dxx][4], acc[dxx][5], acc[dxx][6], acc[dxx][7]};
      __builtin_nontemporal_store(o0, (f4*)op);
      __builtin_nontemporal_store(o1, (f4*)(op + 4));
    }
  }
}

extern "C" void kernel_launch(void* const* d_in, const int* in_sizes, int n_in,
                              void* d_out, int out_size, void* d_ws, size_t ws_size,
                              hipStream_t stream) {
  const float* x = (const float*)d_in[0];
  const float* w = (const float*)d_in[1];
  float* o = (float*)d_out;
  dim3 grid(7168), block(256);
  hipLaunchKernelGGL(wcorr, grid, block, 0, stream, x, w, o);
}

// Round 15
// 220.370 us; speedup vs baseline: 1.1331x; 1.0569x over previous
//
#include <hip/hip_runtime.h>
#include <cstdint>

#define C_ 128
#define L_ 16
#define G_ 4
#define H_ 56
#define W_ 56
#define HW_ 3136
#define CH_ 2                      // channels per chunk
#define NCK_ 16                    // chunks
#define NR_ 5                      // halo rows per wave (r = 2w .. 2w+4)
#define WBUF_F (CH_ * NR_ * 64)    // 640 floats per wave-buffer
#define WL_F 2048                  // weights [c(32)][dy(8)][dx(8)]
#define LDS_F (WL_F + 4 * 2 * WBUF_F)  // 7168 floats = 28672 B
#define XT_ (CH_ * NR_ * 16)       // 160 staging tasks per wave per chunk

typedef float f4 __attribute__((ext_vector_type(4)));
typedef __attribute__((address_space(3))) uint32_t lds_u32;
typedef const __attribute__((address_space(1))) uint32_t glb_u32;

// Block = (b, t, g, htile of 4 rows), 256 thr = 8 tx x 4 h x 8 dy-slots.
// NO main-loop barriers: wave w owns dy {2w,2w+1} -> needs only rows
// 2w..2w+4 of the 10-row halo -> stages its OWN 5-row x CH tile into a
// private LDS region (global_load_lds, 3 calls/chunk), double-buffered,
// synchronized by per-wave counted vmcnt:
//   queue = [stage(k) S<=3][x1 4][stage(k+1) S'>=2] -> s_waitcnt vmcnt(6)
// provably drains stage(k) for all mask cases (S,S' in {2,3}; an all-masked
// 3rd call exists at htile 13 waves 2/3 -> hence 6, not 7). Last iter (no
// stage) waits vmcnt(4). sched_barrier(0) fences the waitcnt (rule #18) and
// the loop top (pins next-stage issue after current ds_reads' lgkm waits,
// closing the WAR hazard on the double buffer by program order).
// xs swizzle: storage block sb holds value block vb = sb ^ (rg&7) (pre-
// swizzled global source, linear LDS dest); vb 0/15 + OOB rows stay zero.
// Weights transposed [c][dy][8] in LDS (2 x b128 broadcast); x1 from global
// (L1-broadcast across dy-slots).
__global__ __launch_bounds__(256, 2)
void wcorr(const float* __restrict__ x, const float* __restrict__ wgt,
           float* __restrict__ out) {
  __shared__ float lds[LDS_F];

  int bid = blockIdx.x;
  // bijective XCD swizzle: nwg = 7168 = 8*896; htile fastest (halo-row reuse)
  int wid = (bid & 7) * 896 + (bid >> 3);
  int htile = wid % 14;
  int rest = wid / 14;             // (b*4+g)*16 + t
  int t = rest & 15;
  int bg = rest >> 4;
  int g = bg & 3;
  int b = bg >> 2;
  int h0 = htile * 4;

  int tid = threadIdx.x;
  int lane = tid & 63;
  int wvu = __builtin_amdgcn_readfirstlane(tid >> 6);  // wave 0..3 (uniform)
  int tx = tid & 7;
  int slot = tid >> 3;
  int h = slot & 3;
  int dy = slot >> 2;              // wave w holds dy in {2w, 2w+1}
  bool active = (dy < 7) && (tx < 7);
  int dyc = dy < 7 ? dy : 6;       // clamp idle dy==7 (wave 3 upper half)
  int txc = tx < 7 ? tx : 6;
  int r = h + dyc;                 // global halo row 0..9
  int lr = r - 2 * wvu;            // local row in wave tile, 0..4
  int t1 = t > 0 ? t - 1 : 0;
  int w0 = 8 * txc;

  // zero xs region (pad slots persist as zero across buffer reuse)
  for (int i = WL_F + tid; i < LDS_F; i += 256) lds[i] = 0.0f;

  // stage weights transposed [c][dy][8], 1/32 folded
  {
    const float sc = 1.0f / 32.0f;
    const float* wsrc = wgt + (size_t)(g * 32) * (L_ * 49) + t * 49;
    #pragma unroll
    for (int j = 0; j < 8; ++j) {
      int idx = tid + j * 256;     // 0..2047
      int c = idx >> 6;
      int rem = idx & 63;
      int dyy = rem >> 3, dxx = rem & 7;
      float v = 0.0f;
      if (dyy < 7 && dxx < 7)
        v = wsrc[(size_t)c * (L_ * 49) + dyy * 7 + dxx] * sc;
      lds[idx] = v;
    }
  }

  const size_t cstride = (size_t)L_ * HW_;
  const float* xg = x + ((size_t)b * C_ + (size_t)g * 32) * cstride;
  const float* x1b = xg + (size_t)t1 * HW_ + (size_t)(h0 + h) * W_ + w0;

  // per-wave staging: task tau = lane + call*64 in [0,160):
  // row = tau>>4 (ci = row/5, lrr = row%5, rg = 2w+lrr), sb = tau&15;
  // slot sb receives value block vb = sb ^ (rg&7).
  auto stage = [&](int call, int kb, int c0) {
    int tau = lane + call * 64;
    int row = tau >> 4;
    int sb = tau & 15;
    int ci = (row >= NR_) ? 1 : 0;
    int lrr = row - ci * NR_;
    int rg = 2 * wvu + lrr;
    int vb = sb ^ (rg & 7);
    int hh = h0 - 3 + rg;
    bool ok = (tau < XT_) && (vb >= 1) && (vb <= 14) && (rg <= 9)
              && (hh >= 0) && (hh < H_);
    const float* src = xg + (size_t)(c0 + ci) * cstride + (size_t)t * HW_
                          + hh * W_ + (vb * 4 - 4);
    float* dst = &lds[WL_F + (wvu * 2 + kb) * WBUF_F + call * 256];
    if (ok)
      __builtin_amdgcn_global_load_lds((glb_u32*)src, (lds_u32*)dst, 16, 0, 0);
  };

  float acc[7][8];
  #pragma unroll
  for (int i = 0; i < 7; ++i)
    #pragma unroll
    for (int p = 0; p < 8; ++p) acc[i][p] = 0.0f;

  __syncthreads();                 // zeros + weights visible; ONLY barrier

  stage(0, 0, 0); stage(1, 0, 0); stage(2, 0, 0);   // chunk 0 -> buf 0

  int s = r & 7;
  #pragma unroll 1
  for (int k = 0; k < NCK_; ++k) {
    __builtin_amdgcn_sched_barrier(0);  // pin: stage(k+1) after iter k-1 reads
    int c0 = k * CH_;
    int kb = k & 1;
    // x1 first (so its consumption leaves the prefetch outstanding)
    const float* x1p0 = x1b + (size_t)(c0 + 0) * cstride;
    const float* x1p1 = x1b + (size_t)(c0 + 1) * cstride;
    f4 a00 = *(const f4*)(x1p0);
    f4 a01 = *(const f4*)(x1p0 + 4);
    f4 a10 = *(const f4*)(x1p1);
    f4 a11 = *(const f4*)(x1p1 + 4);
    if (k + 1 < NCK_) {
      stage(0, kb ^ 1, c0 + CH_);
      stage(1, kb ^ 1, c0 + CH_);
      stage(2, kb ^ 1, c0 + CH_);
      asm volatile("s_waitcnt vmcnt(6)");   // stage(k) drained, prefetch flies
    } else {
      asm volatile("s_waitcnt vmcnt(4)");   // drain stage(NCK-1)
    }
    __builtin_amdgcn_sched_barrier(0);      // rule #18: no ds_read hoisting

    const float* base = &lds[WL_F + (wvu * 2 + kb) * WBUF_F];
    #pragma unroll
    for (int ci = 0; ci < CH_; ++ci) {
      const f4* xsrow = (const f4*)(base + (ci * NR_ + lr) * 64);
      f4 q0 = xsrow[(2 * txc + 0) ^ s];
      f4 q1 = xsrow[(2 * txc + 1) ^ s];
      f4 q2 = xsrow[(2 * txc + 2) ^ s];
      f4 q3 = xsrow[(2 * txc + 3) ^ s];
      const f4* wl = (const f4*)&lds[(c0 + ci) * 64 + dyc * 8];
      f4 wv0 = wl[0];
      f4 wv1 = wl[1];
      f4 a0 = ci ? a10 : a00;
      f4 a1 = ci ? a11 : a01;
      float w7[7] = {wv0.x, wv0.y, wv0.z, wv0.w, wv1.x, wv1.y, wv1.z};
      // rr_[i] = value at col w0-4+i; (p,dx) needs col w0+p+dx-3 -> rr_[p+dx+1]
      float rr_[16] = {q0.x, q0.y, q0.z, q0.w, q1.x, q1.y, q1.z, q1.w,
                       q2.x, q2.y, q2.z, q2.w, q3.x, q3.y, q3.z, q3.w};
      float x1v[8] = {a0.x, a0.y, a0.z, a0.w, a1.x, a1.y, a1.z, a1.w};
      #pragma unroll
      for (int dxx = 0; dxx < 7; ++dxx) {
        #pragma unroll
        for (int p = 0; p < 8; ++p) {
          acc[dxx][p] = fmaf(w7[dxx], x1v[p] * rr_[p + dxx + 1], acc[dxx][p]);
        }
      }
    }
  }

  if (active) {
    #pragma unroll
    for (int dxx = 0; dxx < 7; ++dxx) {
      int och = (dy * 7 + dxx) * G_ + g;
      float* op = out + (((size_t)b * 196 + och) * L_ + t) * (size_t)HW_
                      + (size_t)(h0 + h) * W_ + w0;
      f4 o0 = {acc[dxx][0], acc[dxx][1], acc[dxx][2], acc[dxx][3]};
      f4 o1 = {acc[dxx][4], acc[dxx][5], acc[dxx][6], acc[dxx][7]};
      __builtin_nontemporal_store(o0, (f4*)op);
      __builtin_nontemporal_store(o1, (f4*)(op + 4));
    }
  }
}

extern "C" void kernel_launch(void* const* d_in, const int* in_sizes, int n_in,
                              void* d_out, int out_size, void* d_ws, size_t ws_size,
                              hipStream_t stream) {
  const float* x = (const float*)d_in[0];
  const float* w = (const float*)d_in[1];
  float* o = (float*)d_out;
  dim3 grid(7168), block(256);
  hipLaunchKernelGGL(wcorr, grid, block, 0, stream, x, w, o);
}

// Round 16
// 219.976 us; speedup vs baseline: 1.1351x; 1.0018x over previous
//
#include <hip/hip_runtime.h>
#include <cstdint>

#define C_ 128
#define L_ 16
#define G_ 4
#define H_ 56
#define W_ 56
#define HW_ 3136
#define CH_ 2                      // channels per chunk
#define NCK_ 16                    // chunks
#define NR_ 5                      // halo rows per wave (r = 2w .. 2w+4)
#define WBUF_F 768                 // 12 rows x 64 floats (rows 10,11 dummy)
#define WL_F 2048                  // weights [c(32)][dy(8)][dx(8)]
#define LDS_F (WL_F + 4 * 2 * WBUF_F)  // 8192 floats = 32768 B -> 5 blocks/CU

typedef float f4 __attribute__((ext_vector_type(4)));
typedef __attribute__((address_space(3))) uint32_t lds_u32;
typedef const __attribute__((address_space(1))) uint32_t glb_u32;

// Block = (b, t, g, htile of 4 rows), 256 thr = 8 tx x 4 h x 8 dy-slots.
// r15 structure (no main-loop barriers, per-wave private dbuf staging) made
// BRANCHLESS + statically counted:
//  - all 3 stage calls are full-wave unconditional global_load_lds; lanes
//    whose task is pad/OOB/dummy read a 256 B zeros region in d_ws instead
//    (cndmask'd source pointer, increment 0) -> vmcnt arithmetic is exact:
//    queue at iter top = [stage(k):3][x1:4] -> s_waitcnt vmcnt(4) drains
//    stage(k) precisely; compiler's auto-wait for x1 is a static vmcnt(3),
//    keeping the stage(k+1) prefetch in flight through the FMAs.
//  - 12-row wave buffers absorb the 3rd call's 32 overflow lanes (rows 10,11
//    written with zeros, never read) -> no divergent branch anywhere.
//  - stage source pointers: named per-call registers advanced by a
//    pre-selected per-lane increment (k-invariant selection done once).
//  - s_setprio(1) around the FMA block (independent-wave regime).
// xs swizzle: storage block sb holds value block vb = sb ^ (rg&7) (pre-
// swizzled global source, linear LDS dest); weights transposed [c][dy][8]
// in LDS (2 x b128 broadcast); x1 from global (L1-broadcast across slots).
__global__ __launch_bounds__(256, 2)
void wcorr(const float* __restrict__ x, const float* __restrict__ wgt,
           float* __restrict__ out, const float* __restrict__ zsrc) {
  __shared__ float lds[LDS_F];

  int bid = blockIdx.x;
  // bijective XCD swizzle: nwg = 7168 = 8*896; htile fastest (halo-row reuse)
  int wid = (bid & 7) * 896 + (bid >> 3);
  int htile = wid % 14;
  int rest = wid / 14;             // (b*4+g)*16 + t
  int t = rest & 15;
  int bg = rest >> 4;
  int g = bg & 3;
  int b = bg >> 2;
  int h0 = htile * 4;

  int tid = threadIdx.x;
  int lane = tid & 63;
  int wvu = __builtin_amdgcn_readfirstlane(tid >> 6);  // wave 0..3 (uniform)
  int tx = tid & 7;
  int slot = tid >> 3;
  int h = slot & 3;
  int dy = slot >> 2;              // wave w holds dy in {2w, 2w+1}
  bool active = (dy < 7) && (tx < 7);
  int dyc = dy < 7 ? dy : 6;       // clamp idle dy==7 (wave 3 upper half)
  int txc = tx < 7 ? tx : 6;
  int r = h + dyc;                 // global halo row 0..9
  int lr = r - 2 * wvu;            // local row in wave tile, 0..4
  int t1 = t > 0 ? t - 1 : 0;
  int w0 = 8 * txc;

  const size_t cstride = (size_t)L_ * HW_;
  const float* xg = x + ((size_t)b * C_ + (size_t)g * 32) * cstride;

  // per-call lane-constant staging setup (k-invariant): call j, tau=lane+64j:
  // row=tau>>4 (ci=row>=5, lrr=row-5ci, rg=2w+lrr), sb=tau&15,
  // vb = sb ^ (rg&7); invalid tasks (dummy rows 10/11, pad blocks vb 0/15,
  // OOB hh) read the zeros region and never advance.
  auto mkstage = [&](int j, const float*& sp, ptrdiff_t& inc) {
    int tau = lane + j * 64;
    int row = tau >> 4;
    int ci = (row >= NR_) ? 1 : 0;
    int lrr = row - ci * NR_;
    int rg = 2 * wvu + lrr;
    int vb = (tau & 15) ^ (rg & 7);
    int hh = h0 - 3 + rg;
    bool ok = (row < 2 * NR_) && (vb >= 1) && (vb <= 14)
              && (hh >= 0) && (hh < H_);
    sp = ok ? (xg + (size_t)ci * cstride + (size_t)t * HW_
                  + hh * W_ + (vb * 4 - 4))
            : (zsrc + (lane & 15) * 4);
    inc = ok ? (ptrdiff_t)(CH_ * cstride) : 0;
  };
  const float *sp0, *sp1, *sp2;
  ptrdiff_t in0, in1, in2;
  mkstage(0, sp0, in0);
  mkstage(1, sp1, in1);
  mkstage(2, sp2, in2);

  // prologue: stage chunk 0 -> buf 0 (drained by the weights barrier below)
  {
    float* db = &lds[WL_F + (wvu * 2) * WBUF_F];
    __builtin_amdgcn_global_load_lds((glb_u32*)sp0, (lds_u32*)(db + 0), 16, 0, 0);
    __builtin_amdgcn_global_load_lds((glb_u32*)sp1, (lds_u32*)(db + 256), 16, 0, 0);
    __builtin_amdgcn_global_load_lds((glb_u32*)sp2, (lds_u32*)(db + 512), 16, 0, 0);
    sp0 += in0; sp1 += in1; sp2 += in2;
  }

  // stage weights transposed [c][dy][8], 1/32 folded (2048 = 256 x 8 exact)
  {
    const float sc = 1.0f / 32.0f;
    const float* wsrc = wgt + (size_t)(g * 32) * (L_ * 49) + t * 49;
    #pragma unroll
    for (int j = 0; j < 8; ++j) {
      int idx = tid + j * 256;
      int c = idx >> 6;
      int rem = idx & 63;
      int dyy = rem >> 3, dxx = rem & 7;
      float v = 0.0f;
      if (dyy < 7 && dxx < 7)
        v = wsrc[(size_t)c * (L_ * 49) + dyy * 7 + dxx] * sc;
      lds[idx] = v;
    }
  }

  const float* x1c0 = xg + (size_t)t1 * HW_ + (size_t)(h0 + h) * W_ + w0;
  const float* x1c1 = x1c0 + cstride;

  float acc[7][8];
  #pragma unroll
  for (int i = 0; i < 7; ++i)
    #pragma unroll
    for (int p = 0; p < 8; ++p) acc[i][p] = 0.0f;

  __syncthreads();   // weights visible; drains prologue stage (once); ONLY barrier

  int s = r & 7;
  #pragma unroll 1
  for (int k = 0; k < NCK_; ++k) {
    int kb = k & 1;
    int c0 = k * CH_;
    // x1 loads first: queue = [stage(k):3][x1:4]
    f4 a00 = *(const f4*)(x1c0);
    f4 a01 = *(const f4*)(x1c0 + 4);
    f4 a10 = *(const f4*)(x1c1);
    f4 a11 = *(const f4*)(x1c1 + 4);
    x1c0 += CH_ * cstride;
    x1c1 += CH_ * cstride;

    __builtin_amdgcn_sched_barrier(0);
    asm volatile("s_waitcnt vmcnt(4)" ::: "memory");  // stage(k) landed exactly
    __builtin_amdgcn_sched_barrier(0);

    const float* base = &lds[WL_F + (wvu * 2 + kb) * WBUF_F];
    const f4* xsrow0 = (const f4*)(base + lr * 64);
    const f4* xsrow1 = (const f4*)(base + (NR_ + lr) * 64);
    f4 q00 = xsrow0[(2 * txc + 0) ^ s];
    f4 q01 = xsrow0[(2 * txc + 1) ^ s];
    f4 q02 = xsrow0[(2 * txc + 2) ^ s];
    f4 q03 = xsrow0[(2 * txc + 3) ^ s];
    f4 q10 = xsrow1[(2 * txc + 0) ^ s];
    f4 q11 = xsrow1[(2 * txc + 1) ^ s];
    f4 q12 = xsrow1[(2 * txc + 2) ^ s];
    f4 q13 = xsrow1[(2 * txc + 3) ^ s];
    const f4* wl0 = (const f4*)&lds[(c0 + 0) * 64 + dyc * 8];
    const f4* wl1 = (const f4*)&lds[(c0 + 1) * 64 + dyc * 8];
    f4 wa0 = wl0[0], wa1 = wl0[1];
    f4 wb0 = wl1[0], wb1 = wl1[1];

    if (k + 1 < NCK_) {            // prefetch chunk k+1 -> other buffer
      float* db = &lds[WL_F + (wvu * 2 + (kb ^ 1)) * WBUF_F];
      __builtin_amdgcn_global_load_lds((glb_u32*)sp0, (lds_u32*)(db + 0), 16, 0, 0);
      __builtin_amdgcn_global_load_lds((glb_u32*)sp1, (lds_u32*)(db + 256), 16, 0, 0);
      __builtin_amdgcn_global_load_lds((glb_u32*)sp2, (lds_u32*)(db + 512), 16, 0, 0);
      sp0 += in0; sp1 += in1; sp2 += in2;
    }

    __builtin_amdgcn_s_setprio(1);
    #pragma unroll
    for (int ci = 0; ci < CH_; ++ci) {
      f4 Q0 = ci ? q10 : q00, Q1 = ci ? q11 : q01;
      f4 Q2 = ci ? q12 : q02, Q3 = ci ? q13 : q03;
      f4 W0 = ci ? wb0 : wa0, W1 = ci ? wb1 : wa1;
      f4 A0 = ci ? a10 : a00, A1 = ci ? a11 : a01;
      float w7[7] = {W0.x, W0.y, W0.z, W0.w, W1.x, W1.y, W1.z};
      float rr_[16] = {Q0.x, Q0.y, Q0.z, Q0.w, Q1.x, Q1.y, Q1.z, Q1.w,
                       Q2.x, Q2.y, Q2.z, Q2.w, Q3.x, Q3.y, Q3.z, Q3.w};
      float x1v[8] = {A0.x, A0.y, A0.z, A0.w, A1.x, A1.y, A1.z, A1.w};
      #pragma unroll
      for (int dxx = 0; dxx < 7; ++dxx) {
        #pragma unroll
        for (int p = 0; p < 8; ++p) {
          acc[dxx][p] = fmaf(w7[dxx], x1v[p] * rr_[p + dxx + 1], acc[dxx][p]);
        }
      }
    }
    __builtin_amdgcn_s_setprio(0);
  }

  if (active) {
    #pragma unroll
    for (int dxx = 0; dxx < 7; ++dxx) {
      int och = (dy * 7 + dxx) * G_ + g;
      float* op = out + (((size_t)b * 196 + och) * L_ + t) * (size_t)HW_
                      + (size_t)(h0 + h) * W_ + w0;
      f4 o0 = {acc[dxx][0], acc[dxx][1], acc[dxx][2], acc[dxx][3]};
      f4 o1 = {acc[dxx][4], acc[dxx][5], acc[dxx][6], acc[dxx][7]};
      __builtin_nontemporal_store(o0, (f4*)op);
      __builtin_nontemporal_store(o1, (f4*)(op + 4));
    }
  }
}

extern "C" void kernel_launch(void* const* d_in, const int* in_sizes, int n_in,
                              void* d_out, int out_size, void* d_ws, size_t ws_size,
                              hipStream_t stream) {
  const float* x = (const float*)d_in[0];
  const float* w = (const float*)d_in[1];
  float* o = (float*)d_out;
  // 256 B zeros region for redirected (pad/OOB/dummy) staging lanes
  hipMemsetAsync(d_ws, 0, 256, stream);
  dim3 grid(7168), block(256);
  hipLaunchKernelGGL(wcorr, grid, block, 0, stream, x, w, o, (const float*)d_ws);
}